// Round 1
// baseline (274.398 us; speedup 1.0000x reference)
//
#include <hip/hip_runtime.h>

// Problem constants (shapes fixed by setup_inputs): x1,x2 = [512, 256, 256] f32
static constexpr int LC   = 256 * 256;   // per-sample flattened length
static constexpr int V4   = LC / 4;      // 16384 float4 per sample
static constexpr int TPB  = 1024;        // 512 blocks * 1024 thr = full chip wave capacity

__global__ __launch_bounds__(TPB) void cos_per_sample_kernel(
    const float* __restrict__ x1, const float* __restrict__ x2,
    float* __restrict__ cos_ws)
{
    const size_t base = (size_t)blockIdx.x * LC;
    const float4* a4 = reinterpret_cast<const float4*>(x1 + base);
    const float4* b4 = reinterpret_cast<const float4*>(x2 + base);

    double dot = 0.0, sa = 0.0, sb = 0.0;

    // 16384 float4 / 1024 threads = 16 iterations, coalesced stride
    #pragma unroll 4
    for (int i = threadIdx.x; i < V4; i += TPB) {
        float4 a = a4[i];
        float4 b = b4[i];
        float pd = a.x * b.x + a.y * b.y + a.z * b.z + a.w * b.w;
        float pa = a.x * a.x + a.y * a.y + a.z * a.z + a.w * a.w;
        float pb = b.x * b.x + b.y * b.y + b.z * b.z + b.w * b.w;
        dot += (double)pd;
        sa  += (double)pa;
        sb  += (double)pb;
    }

    // wave64 reduction
    #pragma unroll
    for (int off = 32; off > 0; off >>= 1) {
        dot += __shfl_down(dot, off, 64);
        sa  += __shfl_down(sa,  off, 64);
        sb  += __shfl_down(sb,  off, 64);
    }

    __shared__ double s[3][TPB / 64];   // 16 waves
    const int wave = threadIdx.x >> 6;
    if ((threadIdx.x & 63) == 0) {
        s[0][wave] = dot;
        s[1][wave] = sa;
        s[2][wave] = sb;
    }
    __syncthreads();

    if (threadIdx.x == 0) {
        double D = 0.0, A = 0.0, B = 0.0;
        #pragma unroll
        for (int w = 0; w < TPB / 64; ++w) {
            D += s[0][w];
            A += s[1][w];
            B += s[2][w];
        }
        double denom = sqrt(A) * sqrt(B);
        denom = fmax(denom, 1e-8);
        cos_ws[blockIdx.x] = (float)(D / denom);
    }
}

__global__ void segmented_mean_kernel(const float* __restrict__ cos_ws,
                                      float* __restrict__ out,
                                      int n, int groups)
{
    int g = blockIdx.x * blockDim.x + threadIdx.x;
    if (g < groups) {
        float s = 0.0f;
        for (int j = 0; j < n; ++j) s += cos_ws[g * n + j];
        out[g] = s / (float)n;
    }
}

extern "C" void kernel_launch(void* const* d_in, const int* in_sizes, int n_in,
                              void* d_out, int out_size, void* d_ws, size_t ws_size,
                              hipStream_t stream)
{
    const float* x1 = (const float*)d_in[0];
    const float* x2 = (const float*)d_in[1];
    float* out = (float*)d_out;
    float* ws  = (float*)d_ws;   // 512 floats of per-sample cosine

    const int N      = in_sizes[0] / LC;        // 512 samples
    const int groups = out_size;                // 64
    const int n      = N / groups;              // 8

    cos_per_sample_kernel<<<N, TPB, 0, stream>>>(x1, x2, ws);

    int mtpb = 64;
    int mblocks = (groups + mtpb - 1) / mtpb;
    segmented_mean_kernel<<<mblocks, mtpb, 0, stream>>>(ws, out, n, groups);
}

// Round 2
// 272.880 us; speedup vs baseline: 1.0056x; 1.0056x over previous
//
#include <hip/hip_runtime.h>

// Shapes fixed by setup_inputs(): x1, x2 = [512, 256, 256] float32
static constexpr int LC  = 256 * 256;            // 65536 floats per sample
static constexpr int BPS = 4;                    // blocks per sample
static constexpr int TPB = 256;                  // threads per block
static constexpr int CHUNK4 = (LC / 4) / BPS;    // 4096 float4 per block
static constexpr int ITERS  = CHUNK4 / TPB;      // 16 float4 per thread per array

// Partial reduction: each block reduces a contiguous quarter-sample to
// (dot, |a|^2, |b|^2), written to ws[blk*4 + {0,1,2}].
__global__ __launch_bounds__(TPB, 8) void cos_partial_kernel(
    const float* __restrict__ x1, const float* __restrict__ x2,
    float* __restrict__ ws)
{
    const size_t base4 = (size_t)blockIdx.x * CHUNK4;
    const float4* a4 = reinterpret_cast<const float4*>(x1) + base4;
    const float4* b4 = reinterpret_cast<const float4*>(x2) + base4;

    // 2-way split accumulators to shorten dependency chains
    float dot0 = 0.f, dot1 = 0.f;
    float sa0 = 0.f, sa1 = 0.f;
    float sb0 = 0.f, sb1 = 0.f;

    #pragma unroll
    for (int it = 0; it < ITERS; it += 2) {
        float4 a0 = a4[(size_t)it * TPB + threadIdx.x];
        float4 b0 = b4[(size_t)it * TPB + threadIdx.x];
        float4 a1 = a4[(size_t)(it + 1) * TPB + threadIdx.x];
        float4 b1 = b4[(size_t)(it + 1) * TPB + threadIdx.x];

        dot0 += a0.x * b0.x + a0.y * b0.y + a0.z * b0.z + a0.w * b0.w;
        sa0  += a0.x * a0.x + a0.y * a0.y + a0.z * a0.z + a0.w * a0.w;
        sb0  += b0.x * b0.x + b0.y * b0.y + b0.z * b0.z + b0.w * b0.w;

        dot1 += a1.x * b1.x + a1.y * b1.y + a1.z * b1.z + a1.w * b1.w;
        sa1  += a1.x * a1.x + a1.y * a1.y + a1.z * a1.z + a1.w * a1.w;
        sb1  += b1.x * b1.x + b1.y * b1.y + b1.z * b1.z + b1.w * b1.w;
    }

    float dot = dot0 + dot1;
    float sa  = sa0 + sa1;
    float sb  = sb0 + sb1;

    // wave64 butterfly reduce
    #pragma unroll
    for (int off = 32; off > 0; off >>= 1) {
        dot += __shfl_down(dot, off, 64);
        sa  += __shfl_down(sa,  off, 64);
        sb  += __shfl_down(sb,  off, 64);
    }

    __shared__ float s[3][TPB / 64];   // 4 waves
    const int wave = threadIdx.x >> 6;
    if ((threadIdx.x & 63) == 0) {
        s[0][wave] = dot;
        s[1][wave] = sa;
        s[2][wave] = sb;
    }
    __syncthreads();

    if (threadIdx.x == 0) {
        float D = 0.f, A = 0.f, B = 0.f;
        #pragma unroll
        for (int w = 0; w < TPB / 64; ++w) {
            D += s[0][w];
            A += s[1][w];
            B += s[2][w];
        }
        float* o = ws + (size_t)blockIdx.x * 4;
        o[0] = D;
        o[1] = A;
        o[2] = B;
    }
}

// Finalize: combine 4 partials per sample -> cosine, then segmented mean of n.
// Single block of 512 threads (one per sample).
__global__ __launch_bounds__(512) void cos_finalize_kernel(
    const float* __restrict__ ws, float* __restrict__ out,
    int n_samples, int n, int groups)
{
    __shared__ float cos_s[512];
    const int s = threadIdx.x;
    if (s < n_samples) {
        float D = 0.f, A = 0.f, B = 0.f;
        #pragma unroll
        for (int q = 0; q < BPS; ++q) {
            const float* p = ws + (size_t)(s * BPS + q) * 4;
            D += p[0];
            A += p[1];
            B += p[2];
        }
        float denom = sqrtf(A) * sqrtf(B);
        denom = fmaxf(denom, 1e-8f);
        cos_s[s] = D / denom;
    }
    __syncthreads();
    if (s < groups) {
        float m = 0.f;
        for (int j = 0; j < n; ++j) m += cos_s[s * n + j];
        out[s] = m / (float)n;
    }
}

extern "C" void kernel_launch(void* const* d_in, const int* in_sizes, int n_in,
                              void* d_out, int out_size, void* d_ws, size_t ws_size,
                              hipStream_t stream)
{
    const float* x1 = (const float*)d_in[0];
    const float* x2 = (const float*)d_in[1];
    float* out = (float*)d_out;
    float* ws  = (float*)d_ws;   // BPS*N_samples*4 floats = 32 KB of partials

    const int n_samples = in_sizes[0] / LC;     // 512
    const int groups    = out_size;             // 64
    const int n         = n_samples / groups;   // 8
    const int n_blocks  = n_samples * BPS;      // 2048

    cos_partial_kernel<<<n_blocks, TPB, 0, stream>>>(x1, x2, ws);
    cos_finalize_kernel<<<1, 512, 0, stream>>>(ws, out, n_samples, n, groups);
}

// Round 4
// 248.100 us; speedup vs baseline: 1.1060x; 1.0999x over previous
//
#include <hip/hip_runtime.h>

// Shapes fixed by setup_inputs(): x1, x2 = [512, 256, 256] float32
static constexpr int LC  = 256 * 256;            // 65536 floats per sample
static constexpr int BPS = 4;                    // blocks per sample
static constexpr int TPB = 256;                  // threads per block
static constexpr int CHUNK4 = (LC / 4) / BPS;    // 4096 float4 per block
static constexpr int ITERS  = CHUNK4 / TPB;      // 16 float4 per thread per array

// Native clang vector type — accepted by __builtin_nontemporal_load
typedef float floatx4 __attribute__((ext_vector_type(4)));

// Partial reduction: each block reduces a contiguous quarter-sample to
// (dot, |a|^2, |b|^2), written to ws[blk*4 + {0,1,2}].
__global__ __launch_bounds__(TPB, 8) void cos_partial_kernel(
    const float* __restrict__ x1, const float* __restrict__ x2,
    float* __restrict__ ws)
{
    const size_t base4 = (size_t)blockIdx.x * CHUNK4 + threadIdx.x;
    const floatx4* a4 = reinterpret_cast<const floatx4*>(x1) + base4;
    const floatx4* b4 = reinterpret_cast<const floatx4*>(x2) + base4;

    // 4-way split accumulators; 8 loads in flight per unrolled group.
    float dot0 = 0.f, dot1 = 0.f, dot2 = 0.f, dot3 = 0.f;
    float sa0 = 0.f, sa1 = 0.f, sa2 = 0.f, sa3 = 0.f;
    float sb0 = 0.f, sb1 = 0.f, sb2 = 0.f, sb3 = 0.f;

    #pragma unroll
    for (int it = 0; it < ITERS; it += 4) {
        // Non-temporal: bypass cache hierarchy -> uniform HBM path for all loads
        floatx4 a0 = __builtin_nontemporal_load(&a4[(size_t)(it + 0) * TPB]);
        floatx4 b0 = __builtin_nontemporal_load(&b4[(size_t)(it + 0) * TPB]);
        floatx4 a1 = __builtin_nontemporal_load(&a4[(size_t)(it + 1) * TPB]);
        floatx4 b1 = __builtin_nontemporal_load(&b4[(size_t)(it + 1) * TPB]);
        floatx4 a2 = __builtin_nontemporal_load(&a4[(size_t)(it + 2) * TPB]);
        floatx4 b2 = __builtin_nontemporal_load(&b4[(size_t)(it + 2) * TPB]);
        floatx4 a3 = __builtin_nontemporal_load(&a4[(size_t)(it + 3) * TPB]);
        floatx4 b3 = __builtin_nontemporal_load(&b4[(size_t)(it + 3) * TPB]);

        dot0 += a0.x * b0.x + a0.y * b0.y + a0.z * b0.z + a0.w * b0.w;
        sa0  += a0.x * a0.x + a0.y * a0.y + a0.z * a0.z + a0.w * a0.w;
        sb0  += b0.x * b0.x + b0.y * b0.y + b0.z * b0.z + b0.w * b0.w;

        dot1 += a1.x * b1.x + a1.y * b1.y + a1.z * b1.z + a1.w * b1.w;
        sa1  += a1.x * a1.x + a1.y * a1.y + a1.z * a1.z + a1.w * a1.w;
        sb1  += b1.x * b1.x + b1.y * b1.y + b1.z * b1.z + b1.w * b1.w;

        dot2 += a2.x * b2.x + a2.y * b2.y + a2.z * b2.z + a2.w * b2.w;
        sa2  += a2.x * a2.x + a2.y * a2.y + a2.z * a2.z + a2.w * a2.w;
        sb2  += b2.x * b2.x + b2.y * b2.y + b2.z * b2.z + b2.w * b2.w;

        dot3 += a3.x * b3.x + a3.y * b3.y + a3.z * b3.z + a3.w * b3.w;
        sa3  += a3.x * a3.x + a3.y * a3.y + a3.z * a3.z + a3.w * a3.w;
        sb3  += b3.x * b3.x + b3.y * b3.y + b3.z * b3.z + b3.w * b3.w;
    }

    float dot = (dot0 + dot1) + (dot2 + dot3);
    float sa  = (sa0 + sa1) + (sa2 + sa3);
    float sb  = (sb0 + sb1) + (sb2 + sb3);

    // wave64 butterfly reduce
    #pragma unroll
    for (int off = 32; off > 0; off >>= 1) {
        dot += __shfl_down(dot, off, 64);
        sa  += __shfl_down(sa,  off, 64);
        sb  += __shfl_down(sb,  off, 64);
    }

    __shared__ float s[3][TPB / 64];   // 4 waves
    const int wave = threadIdx.x >> 6;
    if ((threadIdx.x & 63) == 0) {
        s[0][wave] = dot;
        s[1][wave] = sa;
        s[2][wave] = sb;
    }
    __syncthreads();

    if (threadIdx.x == 0) {
        float D = 0.f, A = 0.f, B = 0.f;
        #pragma unroll
        for (int w = 0; w < TPB / 64; ++w) {
            D += s[0][w];
            A += s[1][w];
            B += s[2][w];
        }
        float* o = ws + (size_t)blockIdx.x * 4;
        o[0] = D;
        o[1] = A;
        o[2] = B;
    }
}

// Finalize: combine 4 partials per sample -> cosine, then segmented mean of n.
__global__ __launch_bounds__(512) void cos_finalize_kernel(
    const float* __restrict__ ws, float* __restrict__ out,
    int n_samples, int n, int groups)
{
    __shared__ float cos_s[512];
    const int s = threadIdx.x;
    if (s < n_samples) {
        float D = 0.f, A = 0.f, B = 0.f;
        #pragma unroll
        for (int q = 0; q < BPS; ++q) {
            const float* p = ws + (size_t)(s * BPS + q) * 4;
            D += p[0];
            A += p[1];
            B += p[2];
        }
        float denom = sqrtf(A) * sqrtf(B);
        denom = fmaxf(denom, 1e-8f);
        cos_s[s] = D / denom;
    }
    __syncthreads();
    if (s < groups) {
        float m = 0.f;
        for (int j = 0; j < n; ++j) m += cos_s[s * n + j];
        out[s] = m / (float)n;
    }
}

extern "C" void kernel_launch(void* const* d_in, const int* in_sizes, int n_in,
                              void* d_out, int out_size, void* d_ws, size_t ws_size,
                              hipStream_t stream)
{
    const float* x1 = (const float*)d_in[0];
    const float* x2 = (const float*)d_in[1];
    float* out = (float*)d_out;
    float* ws  = (float*)d_ws;   // BPS*N_samples*4 floats of partials

    const int n_samples = in_sizes[0] / LC;     // 512
    const int groups    = out_size;             // 64
    const int n         = n_samples / groups;   // 8
    const int n_blocks  = n_samples * BPS;      // 2048

    cos_partial_kernel<<<n_blocks, TPB, 0, stream>>>(x1, x2, ws);
    cos_finalize_kernel<<<1, 512, 0, stream>>>(ws, out, n_samples, n, groups);
}